// Round 19
// baseline (128.755 us; speedup 1.0000x reference)
//
#include <hip/hip_runtime.h>

typedef short short8 __attribute__((ext_vector_type(8)));
typedef float f32x4 __attribute__((ext_vector_type(4)));
typedef unsigned long long u64;

#define NE 1024
#define D 64
#define HW 4096
#define MARGIN 3.0e-3f     // t-space margin (proven R3/R5/R12/R13/R15/R18)
#define FLT_MAX_F 3.402823466e+38f
#define MSTRIDE 17         // lmask row stride in u64 (pad: kills bank conflicts)

// ws: bn f32[1024]@0 ; ebf u16[65536]@4096
#define WS_BN  0
#define WS_EBF 4096

__device__ __forceinline__ unsigned short f2bf(float f) {   // RNE f32->bf16
    unsigned u = __float_as_uint(f);
    return (unsigned short)((u + 0x7fffu + ((u >> 16) & 1u)) >> 16);
}

// numpy pairwise sum of squares, n=64 (frozen — exact since R2)
__device__ __forceinline__ float np_sum64_sq(const float* v) {
    float s[8];
#pragma unroll
    for (int j = 0; j < 8; ++j) s[j] = __fmul_rn(v[j], v[j]);
#pragma unroll
    for (int i = 8; i < 64; i += 8) {
#pragma unroll
        for (int j = 0; j < 8; ++j)
            s[j] = __fadd_rn(s[j], __fmul_rn(v[i + j], v[i + j]));
    }
    return __fadd_rn(__fadd_rn(__fadd_rn(s[0], s[1]), __fadd_rn(s[2], s[3])),
                     __fadd_rn(__fadd_rn(s[4], s[5]), __fadd_rn(s[6], s[7])));
}

__global__ __launch_bounds__(256) void kP_prep(
        const float* __restrict__ cb, float* __restrict__ bn,
        unsigned short* __restrict__ ebf) {
    const int gid = blockIdx.x * 256 + threadIdx.x;   // 65536 threads
    ebf[gid] = f2bf(cb[gid]);
    if (gid < NE) {
        float row[D];
        const float4* r4 = reinterpret_cast<const float4*>(cb + (size_t)gid * D);
#pragma unroll
        for (int i = 0; i < 16; ++i) {
            float4 v = r4[i];
            row[4*i+0] = v.x; row[4*i+1] = v.y; row[4*i+2] = v.z; row[4*i+3] = v.w;
        }
        bn[gid] = np_sum64_sq(row);
    }
}

// one block = 64 tokens (16/wave) x all 1024 codes, SINGLE pass:
// C-init MFMA (-bn/2, proven R18), running prefix-threshold marking
// (superset of final-threshold set), frozen-exact in-block rerank.
__global__ __launch_bounds__(256, 4) void k_mega(
        const float* __restrict__ in, const unsigned short* __restrict__ ebf,
        const float* __restrict__ bn_g, const float* __restrict__ cb,
        float* __restrict__ out) {
    __shared__ unsigned short ebq[128 * 64];      // 16 KB staging tile (swizzled)
    __shared__ float sbn[NE];                     // 4 KB  (-0.5*bn)
    __shared__ u64 lmask[64 * MSTRIDE];           // 8.7 KB (fully overwritten)
    __shared__ unsigned short win_s[64];

    const int tid  = threadIdx.x;
    const int lane = tid & 63, w = tid >> 6;
    const int lcol = lane & 15, lhi = lane >> 4, lrow = lhi * 4;
    const int tokw = blockIdx.x * 64 + w * 16;    // wave's 16 tokens
    const int b = tokw >> 12, hwb = tokw & 4095;

#pragma unroll
    for (int i = 0; i < 4; ++i)
        sbn[tid + i * 256] = __fmul_rn(-0.5f, bn_g[tid + i * 256]);  // exact *0.5

    // B fragments (frozen build, proven R4-R18; one 16-token half only)
    const float* xbase = in + (size_t)b * (D * HW);
    const int hw0 = hwb + lcol;
    const int kb = lhi * 8;
    short8 B00, B01;
    {
        const float* p;
        p = xbase + (size_t)kb * HW + hw0;
#pragma unroll
        for (int j = 0; j < 8; ++j) B00[j] = (short)f2bf(p[(size_t)j * HW]);
        p = xbase + (size_t)(kb + 32) * HW + hw0;
#pragma unroll
        for (int j = 0; j < 8; ++j) B01[j] = (short)f2bf(p[(size_t)j * HW]);
    }

    const int swz   = (lcol & 7) << 4;
    const int aoff0 = lcol * 128 + ((lhi * 16) ^ swz);
    const int aoff1 = lcol * 128 + ((64 + lhi * 16) ^ swz);

    int4 pf0, pf1, pf2, pf3;   // prefetch registers (async-split, proven R17/R18)
#define LOADC(C) { const int4* s_ = (const int4*)(ebf + (size_t)(C) * 8192);  \
                   pf0 = s_[tid]; pf1 = s_[tid + 256];                        \
                   pf2 = s_[tid + 512]; pf3 = s_[tid + 768]; }
#define WRITEC() { int4 t_[4] = {pf0, pf1, pf2, pf3};                         \
    _Pragma("unroll")                                                         \
    for (int i = 0; i < 4; ++i) {                                             \
        int L = (tid + i * 256) * 16;                                         \
        int row = L >> 7, wi = L & 127;                                       \
        *(int4*)((char*)ebq + row * 128 + (wi ^ ((row & 7) << 4))) = t_[i];   \
    } }

    // ---- single pass: MFMA -> running vmax -> prefix-threshold mark ----
    f32x4 vA = {-FLT_MAX_F, -FLT_MAX_F, -FLT_MAX_F, -FLT_MAX_F};  // 4 indep chains
    const int tl = w * 16 + lcol;                 // token-local index (0..63)
    float acc32[32];                              // chunk stash (const-indexed)

    LOADC(0)
    WRITEC()
    __syncthreads();
    for (int c = 0; c < 8; ++c) {
        if (c < 7) LOADC(c + 1)                  // next chunk in flight
#pragma unroll
        for (int ct = 0; ct < 8; ++ct) {
            const char* lp = (const char*)ebq + ct * 2048;
            short8 A0 = *(const short8*)(lp + aoff0);
            short8 A1 = *(const short8*)(lp + aoff1);
            f32x4 acc = *(const f32x4*)(sbn + c * 128 + ct * 16 + lrow);  // C-init
            acc = __builtin_amdgcn_mfma_f32_16x16x32_bf16(A0, B00, acc, 0, 0, 0);
            acc = __builtin_amdgcn_mfma_f32_16x16x32_bf16(A1, B01, acc, 0, 0, 0);
#pragma unroll
            for (int r = 0; r < 4; ++r) {
                acc32[ct * 4 + r] = acc[r];
                vA[r] = fmaxf(vA[r], acc[r]);
            }
        }
        // chunk-inclusive running max across the token's 4 lhi lanes
        float v0 = fmaxf(fmaxf(vA[0], vA[1]), fmaxf(vA[2], vA[3]));
        v0 = fmaxf(v0, __shfl_xor(v0, 16));
        v0 = fmaxf(v0, __shfl_xor(v0, 32));
        const float athr = v0 - 0.5f * MARGIN;   // acc-space threshold (R18-proven)
        // mark: prefix threshold >= ... superset of final-threshold set
        u64 w0 = 0, w1 = 0;
#pragma unroll
        for (int ct = 0; ct < 8; ++ct) {
#pragma unroll
            for (int r = 0; r < 4; ++r) {
                const int bit = (ct & 3) * 16 + lrow + r;
                if (acc32[ct * 4 + r] >= athr) {
                    if (ct < 4) w0 |= 1ull << bit; else w1 |= 1ull << bit;
                }
            }
        }
        w0 |= __shfl_xor(w0, 16); w0 |= __shfl_xor(w0, 32);
        w1 |= __shfl_xor(w1, 16); w1 |= __shfl_xor(w1, 32);
        if (lhi == 0) {
            lmask[tl * MSTRIDE + 2 * c]     = w0;
            lmask[tl * MSTRIDE + 2 * c + 1] = w1;
        }
        __syncthreads();                         // everyone done reading ebq
        if (c < 7) {
            WRITEC()
            __syncthreads();                     // next chunk visible
        }
    }
    __syncthreads();

    // ---- rerank: 4 threads/token, frozen-exact, order-independent key min ----
    {
        const int tok_l = tid >> 2, sub = tid & 3;
        const int tok = blockIdx.x * 64 + tok_l;
        const int tb = tok >> 12, thw = tok & 4095;
        const float* x = in + (size_t)tb * (D * HW) + thw;
        float xv[D];
#pragma unroll
        for (int d = 0; d < D; ++d) xv[d] = x[(size_t)d * HW];
        const float a = np_sum64_sq(xv);                      // frozen

        u64 best = ~0ull;
        int kp = -1;
        int pos = 0;
        for (int wd = 0; wd < 16; ++wd) {
            u64 m = lmask[tok_l * MSTRIDE + wd];
            while (m) {
                const int k = wd * 64 + (int)__builtin_ctzll(m);
                m &= m - 1;
                if (((pos++) & 3) != sub) continue;
                if (kp < 0) { kp = k; continue; }
                // pair: two independent frozen chains (each sequential asc d)
                const float* e0 = cb + (size_t)kp * D;
                const float* e1 = cb + (size_t)k * D;
                float d0 = 0.f, d1 = 0.f;
#pragma unroll
                for (int d = 0; d < 64; ++d) {
                    d0 = __fmaf_rn(xv[d], e0[d], d0);
                    d1 = __fmaf_rn(xv[d], e1[d], d1);
                }
                float q0 = __fsub_rn(__fadd_rn(a, bn_g[kp]), __fmul_rn(2.0f, d0));
                float q1 = __fsub_rn(__fadd_rn(a, bn_g[k]),  __fmul_rn(2.0f, d1));
                u64 key0 = (((u64)__float_as_uint(q0)) << 32) | (unsigned)kp;
                u64 key1 = (((u64)__float_as_uint(q1)) << 32) | (unsigned)k;
                u64 kmin = key0 < key1 ? key0 : key1;
                best = best < kmin ? best : kmin;
                kp = -1;
            }
        }
        if (kp >= 0) {
            const float* e0 = cb + (size_t)kp * D;
            float d0 = 0.f;
#pragma unroll
            for (int d = 0; d < 64; ++d) d0 = __fmaf_rn(xv[d], e0[d], d0);
            float q0 = __fsub_rn(__fadd_rn(a, bn_g[kp]), __fmul_rn(2.0f, d0));
            u64 key0 = (((u64)__float_as_uint(q0)) << 32) | (unsigned)kp;
            best = best < key0 ? best : key0;
        }
#pragma unroll
        for (int o = 1; o < 4; o <<= 1) {        // tid^1, tid^2: same token group
            u64 v = __shfl_xor(best, o);
            best = best < v ? best : v;
        }
        if (sub == 0) win_s[tok_l] = (unsigned short)(best & 0x3FFull);
    }
    __syncthreads();

    // ---- gather: 4 threads/token write the winning codebook row ----
    {
        const int tok_l = tid >> 2, qd = (tid & 3) << 4;
        const int tok = blockIdx.x * 64 + tok_l;
        const int gb = tok >> 12, ghw = tok & 4095;
        const unsigned k = win_s[tok_l];
        const float4* er = reinterpret_cast<const float4*>(cb + (size_t)k * D + qd);
        float* ot = out + (size_t)gb * (D * HW) + ghw;
#pragma unroll
        for (int i = 0; i < 4; ++i) {
            float4 e = er[i];
            ot[(size_t)(qd + 4*i + 0) * HW] = e.x;
            ot[(size_t)(qd + 4*i + 1) * HW] = e.y;
            ot[(size_t)(qd + 4*i + 2) * HW] = e.z;
            ot[(size_t)(qd + 4*i + 3) * HW] = e.w;
        }
    }
}

extern "C" void kernel_launch(void* const* d_in, const int* in_sizes, int n_in,
                              void* d_out, int out_size, void* d_ws, size_t ws_size,
                              hipStream_t stream) {
    const float* in  = (const float*)d_in[0];
    const float* cb  = (const float*)d_in[1];
    float*       out = (float*)d_out;
    char*        ws  = (char*)d_ws;

    float*          bn  = (float*)(ws + WS_BN);
    unsigned short* ebf = (unsigned short*)(ws + WS_EBF);

    hipLaunchKernelGGL(kP_prep, dim3(256),  dim3(256), 0, stream, cb, bn, ebf);
    hipLaunchKernelGGL(k_mega,  dim3(1024), dim3(256), 0, stream, in, ebf, bn, cb, out);
}

// Round 20
// 75.257 us; speedup vs baseline: 1.7109x; 1.7109x over previous
//
#include <hip/hip_runtime.h>

typedef short short8 __attribute__((ext_vector_type(8)));
typedef float f32x4 __attribute__((ext_vector_type(4)));
typedef unsigned long long u64;

#define NE 1024
#define D 64
#define HW 4096
#define MARGIN 3.0e-3f     // t-space margin (proven R3/R5/R12/R13/R15/R18)
#define FLT_MAX_F 3.402823466e+38f
#define MSTRIDE 17         // lmask row stride in u64 (pad: kills bank conflicts)

// ws: bn f32[1024]@0 ; ebf u16[65536]@4096
#define WS_BN  0
#define WS_EBF 4096

__device__ __forceinline__ unsigned short f2bf(float f) {   // RNE f32->bf16
    unsigned u = __float_as_uint(f);
    return (unsigned short)((u + 0x7fffu + ((u >> 16) & 1u)) >> 16);
}

// numpy pairwise sum of squares, n=64 (frozen — exact since R2)
__device__ __forceinline__ float np_sum64_sq(const float* v) {
    float s[8];
#pragma unroll
    for (int j = 0; j < 8; ++j) s[j] = __fmul_rn(v[j], v[j]);
#pragma unroll
    for (int i = 8; i < 64; i += 8) {
#pragma unroll
        for (int j = 0; j < 8; ++j)
            s[j] = __fadd_rn(s[j], __fmul_rn(v[i + j], v[i + j]));
    }
    return __fadd_rn(__fadd_rn(__fadd_rn(s[0], s[1]), __fadd_rn(s[2], s[3])),
                     __fadd_rn(__fadd_rn(s[4], s[5]), __fadd_rn(s[6], s[7])));
}

__global__ __launch_bounds__(256) void kP_prep(
        const float* __restrict__ cb, float* __restrict__ bn,
        unsigned short* __restrict__ ebf) {
    const int gid = blockIdx.x * 256 + threadIdx.x;   // 65536 threads
    ebf[gid] = f2bf(cb[gid]);
    if (gid < NE) {
        float row[D];
        const float4* r4 = reinterpret_cast<const float4*>(cb + (size_t)gid * D);
#pragma unroll
        for (int i = 0; i < 16; ++i) {
            float4 v = r4[i];
            row[4*i+0] = v.x; row[4*i+1] = v.y; row[4*i+2] = v.z; row[4*i+3] = v.w;
        }
        bn[gid] = np_sum64_sq(row);
    }
}

// 512 threads / 8 waves, 128 tokens/block (16 per wave), all 1024 codes.
// R18's exact two-pass double-buffered structure (1 barrier/phase), 2x waves.
__global__ __launch_bounds__(512, 2) void k_mega(
        const float* __restrict__ in, const unsigned short* __restrict__ ebf,
        const float* __restrict__ bn_g, const float* __restrict__ cb,
        float* __restrict__ out) {
    __shared__ unsigned short ebq[2 * 128 * 64];  // 32 KB double-buffered tile
    __shared__ float sbn[NE];                     // 4 KB  (-0.5*bn)
    __shared__ u64 lmask[128 * MSTRIDE];          // 17 KB (fully overwritten)
    __shared__ unsigned short win_s[128];

    const int tid  = threadIdx.x;
    const int lane = tid & 63, w = tid >> 6;      // w in 0..7
    const int lcol = lane & 15, lhi = lane >> 4, lrow = lhi * 4;
    const int tokw = blockIdx.x * 128 + w * 16;   // wave's 16 tokens
    const int b = tokw >> 12, hwb = tokw & 4095;

#pragma unroll
    for (int i = 0; i < 2; ++i)
        sbn[tid + i * 512] = __fmul_rn(-0.5f, bn_g[tid + i * 512]);  // exact *0.5

    // B fragments (frozen build, proven R4-R19; 16 tokens/wave: B00,B01 only)
    const float* xbase = in + (size_t)b * (D * HW);
    const int hw0 = hwb + lcol;
    const int kb = lhi * 8;
    short8 B00, B01;
    {
        const float* p;
        p = xbase + (size_t)kb * HW + hw0;
#pragma unroll
        for (int j = 0; j < 8; ++j) B00[j] = (short)f2bf(p[(size_t)j * HW]);
        p = xbase + (size_t)(kb + 32) * HW + hw0;
#pragma unroll
        for (int j = 0; j < 8; ++j) B01[j] = (short)f2bf(p[(size_t)j * HW]);
    }

    const int swz   = (lcol & 7) << 4;
    const int aoff0 = lcol * 128 + ((lhi * 16) ^ swz);
    const int aoff1 = lcol * 128 + ((64 + lhi * 16) ^ swz);

    int4 pf0, pf1;   // prefetch registers (2 int4/thread at 512 threads)
#define LOADC(C) { const int4* s_ = (const int4*)(ebf + (size_t)(C) * 8192);  \
                   pf0 = s_[tid]; pf1 = s_[tid + 512]; }
#define WRITEC(BUF) { int4 t_[2] = {pf0, pf1};                                \
    _Pragma("unroll")                                                         \
    for (int i = 0; i < 2; ++i) {                                             \
        int L = (tid + i * 512) * 16;                                         \
        int row = L >> 7, wi = L & 127;                                       \
        *(int4*)((char*)ebq + (BUF) * 16384 + row * 128                       \
                 + (wi ^ ((row & 7) << 4))) = t_[i];                          \
    } }

// C-init: acc starts at -bn/2 -> acc = dot - bn/2 ; min t <=> max acc (R18)
#define CHUNK_MFMA(BUF, C, CT)                                                \
    const char* lp = (const char*)ebq + (BUF) * 16384 + (CT) * 2048;          \
    short8 A0 = *(const short8*)(lp + aoff0);                                 \
    short8 A1 = *(const short8*)(lp + aoff1);                                 \
    f32x4 acc = *(const f32x4*)(sbn + (C) * 128 + (CT) * 16 + lrow);          \
    acc = __builtin_amdgcn_mfma_f32_16x16x32_bf16(A0, B00, acc, 0, 0, 0);     \
    acc = __builtin_amdgcn_mfma_f32_16x16x32_bf16(A1, B01, acc, 0, 0, 0);

    // ---- pass A: per-token MAX of acc over all chunks (4 indep chains) ----
    f32x4 vA = {-FLT_MAX_F, -FLT_MAX_F, -FLT_MAX_F, -FLT_MAX_F};
    LOADC(0)
    WRITEC(0)
    __syncthreads();
    for (int c = 0; c < 8; ++c) {
        const int buf = c & 1;
        if (c < 7) LOADC(c + 1)
#pragma unroll
        for (int ct = 0; ct < 8; ++ct) {
            CHUNK_MFMA(buf, c, ct)
#pragma unroll
            for (int r = 0; r < 4; ++r) vA[r] = fmaxf(vA[r], acc[r]);
        }
        if (c < 7) WRITEC(buf ^ 1)
        __syncthreads();
    }
    float v0 = fmaxf(fmaxf(vA[0], vA[1]), fmaxf(vA[2], vA[3]));
    v0 = fmaxf(v0, __shfl_xor(v0, 16)); v0 = fmaxf(v0, __shfl_xor(v0, 32));
    const float athr = v0 - 0.5f * MARGIN;        // acc-space threshold (R18)
    const int tl = w * 16 + lcol;                 // token-local index (0..127)

    // ---- pass B: bit-identical recompute; compare-only marks, shfl-OR ----
    LOADC(0)
    WRITEC(0)
    __syncthreads();
    for (int c = 0; c < 8; ++c) {
        const int buf = c & 1;
        if (c < 7) LOADC(c + 1)
        u64 w0 = 0, w1 = 0;
#pragma unroll
        for (int ct = 0; ct < 8; ++ct) {
            CHUNK_MFMA(buf, c, ct)
#pragma unroll
            for (int r = 0; r < 4; ++r) {
                const int bit = (ct & 3) * 16 + lrow + r;   // j & 63
                if (acc[r] >= athr) { if (ct < 4) w0 |= 1ull << bit; else w1 |= 1ull << bit; }
            }
        }
        w0 |= __shfl_xor(w0, 16); w0 |= __shfl_xor(w0, 32);
        w1 |= __shfl_xor(w1, 16); w1 |= __shfl_xor(w1, 32);
        if (lhi == 0) {
            lmask[tl * MSTRIDE + 2 * c]     = w0;
            lmask[tl * MSTRIDE + 2 * c + 1] = w1;
        }
        if (c < 7) WRITEC(buf ^ 1)
        __syncthreads();
    }

    // ---- rerank: 4 threads/token, frozen-exact, order-independent key min ----
    {
        const int tok_l = tid >> 2, sub = tid & 3;
        const int tok = blockIdx.x * 128 + tok_l;
        const int tb = tok >> 12, thw = tok & 4095;
        const float* x = in + (size_t)tb * (D * HW) + thw;
        float xv[D];
#pragma unroll
        for (int d = 0; d < D; ++d) xv[d] = x[(size_t)d * HW];
        const float a = np_sum64_sq(xv);                      // frozen

        u64 best = ~0ull;
        int kp = -1;
        int pos = 0;
        for (int wd = 0; wd < 16; ++wd) {
            u64 m = lmask[tok_l * MSTRIDE + wd];
            while (m) {
                const int k = wd * 64 + (int)__builtin_ctzll(m);
                m &= m - 1;
                if (((pos++) & 3) != sub) continue;
                if (kp < 0) { kp = k; continue; }
                // pair: two independent frozen chains (each sequential asc d)
                const float* e0 = cb + (size_t)kp * D;
                const float* e1 = cb + (size_t)k * D;
                float d0 = 0.f, d1 = 0.f;
#pragma unroll
                for (int d = 0; d < 64; ++d) {
                    d0 = __fmaf_rn(xv[d], e0[d], d0);
                    d1 = __fmaf_rn(xv[d], e1[d], d1);
                }
                float q0 = __fsub_rn(__fadd_rn(a, bn_g[kp]), __fmul_rn(2.0f, d0));
                float q1 = __fsub_rn(__fadd_rn(a, bn_g[k]),  __fmul_rn(2.0f, d1));
                u64 key0 = (((u64)__float_as_uint(q0)) << 32) | (unsigned)kp;
                u64 key1 = (((u64)__float_as_uint(q1)) << 32) | (unsigned)k;
                u64 kmin = key0 < key1 ? key0 : key1;
                best = best < kmin ? best : kmin;
                kp = -1;
            }
        }
        if (kp >= 0) {
            const float* e0 = cb + (size_t)kp * D;
            float d0 = 0.f;
#pragma unroll
            for (int d = 0; d < 64; ++d) d0 = __fmaf_rn(xv[d], e0[d], d0);
            float q0 = __fsub_rn(__fadd_rn(a, bn_g[kp]), __fmul_rn(2.0f, d0));
            u64 key0 = (((u64)__float_as_uint(q0)) << 32) | (unsigned)kp;
            best = best < key0 ? best : key0;
        }
#pragma unroll
        for (int o = 1; o < 4; o <<= 1) {        // 4 sub-lanes share a wave
            u64 v = __shfl_xor(best, o);
            best = best < v ? best : v;
        }
        if (sub == 0) win_s[tok_l] = (unsigned short)(best & 0x3FFull);
    }
    __syncthreads();

    // ---- gather: 4 threads/token write the winning codebook row ----
    {
        const int tok_l = tid >> 2, qd = (tid & 3) << 4;
        const int tok = blockIdx.x * 128 + tok_l;
        const int gb = tok >> 12, ghw = tok & 4095;
        const unsigned k = win_s[tok_l];
        const float4* er = reinterpret_cast<const float4*>(cb + (size_t)k * D + qd);
        float* ot = out + (size_t)gb * (D * HW) + ghw;
#pragma unroll
        for (int i = 0; i < 4; ++i) {
            float4 e = er[i];
            ot[(size_t)(qd + 4*i + 0) * HW] = e.x;
            ot[(size_t)(qd + 4*i + 1) * HW] = e.y;
            ot[(size_t)(qd + 4*i + 2) * HW] = e.z;
            ot[(size_t)(qd + 4*i + 3) * HW] = e.w;
        }
    }
}

extern "C" void kernel_launch(void* const* d_in, const int* in_sizes, int n_in,
                              void* d_out, int out_size, void* d_ws, size_t ws_size,
                              hipStream_t stream) {
    const float* in  = (const float*)d_in[0];
    const float* cb  = (const float*)d_in[1];
    float*       out = (float*)d_out;
    char*        ws  = (char*)d_ws;

    float*          bn  = (float*)(ws + WS_BN);
    unsigned short* ebf = (unsigned short*)(ws + WS_EBF);

    hipLaunchKernelGGL(kP_prep, dim3(256), dim3(256), 0, stream, cb, bn, ebf);
    hipLaunchKernelGGL(k_mega,  dim3(512), dim3(512), 0, stream, in, ebf, bn, cb, out);
}